// Round 2
// baseline (118.030 us; speedup 1.0000x reference)
//
#include <hip/hip_runtime.h>
#include <hip/hip_bf16.h>
#include <cstdint>
#include <cstddef>

#define NG 32
#define NP 64
#define ND 512
#define HW 192
#define EPSV 1e-5f

typedef _Float16 half8 __attribute__((ext_vector_type(8)));
typedef float floatx4 __attribute__((ext_vector_type(4)));

// ---------------- pre-pass: [B][ND][HW] f32 -> [B][HW][ND] fp16 (both tensors, one launch)
__global__ __launch_bounds__(256) void transpose_cvt_all(const float* __restrict__ gal,
                                                         const float* __restrict__ prob,
                                                         _Float16* __restrict__ galT,
                                                         _Float16* __restrict__ probT) {
  __shared__ float tile[32][33];
  const int z = blockIdx.z;
  const float* sp;
  _Float16* dp;
  if (z < NP) {
    sp = prob + (size_t)z * ND * HW;
    dp = probT + (size_t)z * HW * ND;
  } else {
    sp = gal + (size_t)(z - NP) * ND * HW;
    dp = galT + (size_t)(z - NP) * HW * ND;
  }
  const int k0 = blockIdx.x * 32;  // ND dim
  const int s0 = blockIdx.y * 32;  // HW dim
  const int tx = threadIdx.x & 31, ty = threadIdx.x >> 5;
#pragma unroll
  for (int i = ty; i < 32; i += 8)
    tile[i][tx] = sp[(size_t)(k0 + i) * HW + s0 + tx];
  __syncthreads();
#pragma unroll
  for (int i = ty; i < 32; i += 8)
    dp[(size_t)(s0 + i) * ND + k0 + tx] = (_Float16)tile[tx][i];
}

// ---------------- async 16B global -> LDS ----------------
__device__ __forceinline__ void g2l16(const void* g, void* l) {
  __builtin_amdgcn_global_load_lds(
      (const __attribute__((address_space(1))) void*)g,
      (__attribute__((address_space(3))) void*)l, 16, 0, 0);
}

// ---------------- main fused kernel: one WG per (g,p) pair ----------------
// A = probT[p] : [192][512] fp16 (rows = y), B = galT[g] : [192][512] (rows = x)
// S[y][x] = sum_k A[y][k] * B[x][k].  8 waves in 4(row) x 2(col) grid; each wave
// computes 48x96 via 3x6 fragments of mfma_f32_16x16x32_f16.
// K-tile = 64 halves (128 B/row, 24 KB/operand), DOUBLE-buffered: stage k+1
// before computing k; one __syncthreads per K-step (implicit vmcnt(0) drain
// lands after the whole compute phase -> load latency hidden).
__global__ __launch_bounds__(512) void qaconv_main(
    const _Float16* __restrict__ galT, const _Float16* __restrict__ probT,
    const float* __restrict__ bn_w, const float* __restrict__ bn_b,
    const float* __restrict__ bn_m, const float* __restrict__ bn_v,
    const float* __restrict__ fc_w, const float* __restrict__ fc_b,
    const float* __restrict__ lbn_w, const float* __restrict__ lbn_b,
    const float* __restrict__ lbn_m, const float* __restrict__ lbn_v,
    float* __restrict__ out) {
  // Swizzle: LDS (row, slot t) holds data slot s = t ^ (row&7)  (16B slots).
  __shared__ __align__(16) char lds[2][2][HW * 128];  // [buf][A=0/B=1], 96 KB
  __shared__ float colpart[4][HW];
  __shared__ float rowpart[2][HW];
  __shared__ float wsum[8];

  const int bid = blockIdx.x;
  const int g = bid >> 6, p = bid & 63;
  const int t = threadIdx.x;
  const int lane = t & 63, wid = t >> 6;
  const int wr = wid & 3;       // wave row (0..3): y-block of 48
  const int wcc = wid >> 2;     // wave col (0..1): x-block of 96
  const int l15 = lane & 15, lhi = lane >> 4;

  const _Float16* pA = probT + (size_t)p * HW * ND;
  const _Float16* pB = galT + (size_t)g * HW * ND;

  floatx4 acc[3][6];
#pragma unroll
  for (int i = 0; i < 3; ++i)
#pragma unroll
    for (int j = 0; j < 6; ++j) acc[i][j] = (floatx4){0.f, 0.f, 0.f, 0.f};

  // staging geometry: 512 threads; srow = row within 64-row round, sslot = 16B slot
  const int srow = t >> 3;
  const int sslot = t & 7;
  const int s = sslot ^ (srow & 7);  // pre-swizzled global source slot (dest stays linear)
  const _Float16* gAp = pA + (size_t)srow * ND + s * 8;
  const _Float16* gBp = pB + (size_t)srow * ND + s * 8;
  const int ldst = wid * 1024;  // wave-uniform LDS dest base (+ lane*16 by HW)

  // prologue: stage kt=0 into buf 0
#pragma unroll
  for (int r = 0; r < 3; ++r) {
    g2l16(gAp + (size_t)r * 64 * ND, lds[0][0] + r * 8192 + ldst);
    g2l16(gBp + (size_t)r * 64 * ND, lds[0][1] + r * 8192 + ldst);
  }

  int cur = 0;
#pragma unroll 2
  for (int kt = 0; kt < 8; ++kt) {
    __syncthreads();  // drains vmcnt(0): buf[cur] staged everywhere; buf[cur^1] reads done
    if (kt < 7) {
      const int kb = (kt + 1) * 64;
#pragma unroll
      for (int r = 0; r < 3; ++r) {
        g2l16(gAp + (size_t)r * 64 * ND + kb, lds[cur ^ 1][0] + r * 8192 + ldst);
        g2l16(gBp + (size_t)r * 64 * ND + kb, lds[cur ^ 1][1] + r * 8192 + ldst);
      }
    }
    const char* LA = lds[cur][0];
    const char* LB = lds[cur][1];
#pragma unroll
    for (int ks = 0; ks < 2; ++ks) {
      half8 af[3], bf[6];
      const int sl = ks * 4 + lhi;
#pragma unroll
      for (int fr = 0; fr < 3; ++fr) {
        const int ry = wr * 48 + fr * 16 + l15;
        af[fr] = *(const half8*)(LA + ry * 128 + ((sl ^ (ry & 7)) << 4));
      }
#pragma unroll
      for (int fn = 0; fn < 6; ++fn) {
        const int rx = wcc * 96 + fn * 16 + l15;
        bf[fn] = *(const half8*)(LB + rx * 128 + ((sl ^ (rx & 7)) << 4));
      }
      __builtin_amdgcn_s_setprio(1);
#pragma unroll
      for (int fr = 0; fr < 3; ++fr)
#pragma unroll
        for (int fn = 0; fn < 6; ++fn)
          acc[fr][fn] =
              __builtin_amdgcn_mfma_f32_16x16x32_f16(af[fr], bf[fn], acc[fr][fn], 0, 0, 0);
      __builtin_amdgcn_s_setprio(0);
    }
    cur ^= 1;
  }

  // ---- epilogue: dual-axis max ----
  // C/D mapping: col(x) = lane&15 (+fn*16+wcc*96), row(y) = (lane>>4)*4+r (+fr*16+wr*48)
  float cm[6];
#pragma unroll
  for (int fn = 0; fn < 6; ++fn) {
    float v = -3.4e38f;
#pragma unroll
    for (int fr = 0; fr < 3; ++fr)
#pragma unroll
      for (int r = 0; r < 4; ++r) v = fmaxf(v, acc[fr][fn][r]);
    v = fmaxf(v, __shfl_xor(v, 16));
    v = fmaxf(v, __shfl_xor(v, 32));
    cm[fn] = v;  // colmax over this wave's 48 y-rows
  }
  if (lane < 16) {
#pragma unroll
    for (int fn = 0; fn < 6; ++fn) colpart[wr][wcc * 96 + fn * 16 + lane] = cm[fn];
  }
  float rm[3][4];
#pragma unroll
  for (int fr = 0; fr < 3; ++fr)
#pragma unroll
    for (int r = 0; r < 4; ++r) {
      float v = acc[fr][0][r];
#pragma unroll
      for (int fn = 1; fn < 6; ++fn) v = fmaxf(v, acc[fr][fn][r]);
      v = fmaxf(v, __shfl_xor(v, 1));
      v = fmaxf(v, __shfl_xor(v, 2));
      v = fmaxf(v, __shfl_xor(v, 4));
      v = fmaxf(v, __shfl_xor(v, 8));
      rm[fr][r] = v;  // rowmax over this wave's 96 x-cols
    }
  if (l15 == 0) {
#pragma unroll
    for (int fr = 0; fr < 3; ++fr)
#pragma unroll
      for (int r = 0; r < 4; ++r)
        rowpart[wcc][wr * 48 + fr * 16 + lhi * 4 + r] = rm[fr][r];
  }
  __syncthreads();

  // ---- fused BN -> fc dot -> logit BN -> sigmoid ----
  float partial = 0.f;
  if (t < 2 * HW) {
    float v;
    if (t < HW)
      v = fmaxf(fmaxf(colpart[0][t], colpart[1][t]), fmaxf(colpart[2][t], colpart[3][t]));
    else {
      const int y = t - HW;
      v = fmaxf(rowpart[0][y], rowpart[1][y]);
    }
    const float sc = (v - bn_m[0]) * (bn_w[0] / sqrtf(bn_v[0] + EPSV)) + bn_b[0];
    partial = sc * fc_w[t];
  }
#pragma unroll
  for (int off = 1; off < 64; off <<= 1) partial += __shfl_xor(partial, off);
  if (lane == 0) wsum[wid] = partial;
  __syncthreads();
  if (t == 0) {
    float sum = fc_b[0];
#pragma unroll
    for (int i = 0; i < 8; ++i) sum += wsum[i];
    const float logit = (sum - lbn_m[0]) * (lbn_w[0] / sqrtf(lbn_v[0] + EPSV)) + lbn_b[0];
    out[bid] = 1.f / (1.f + expf(-logit * 0.1f));
  }
}

// ---------------- naive f32 fallback (only if ws too small) ----------------
__global__ __launch_bounds__(256) void qaconv_naive(
    const float* __restrict__ gal, const float* __restrict__ prob,
    const float* __restrict__ bn_w, const float* __restrict__ bn_b,
    const float* __restrict__ bn_m, const float* __restrict__ bn_v,
    const float* __restrict__ fc_w, const float* __restrict__ fc_b,
    const float* __restrict__ lbn_w, const float* __restrict__ lbn_b,
    const float* __restrict__ lbn_m, const float* __restrict__ lbn_v,
    float* __restrict__ out) {
  __shared__ float prow[ND];
  __shared__ float rowmaxs[HW];
  __shared__ float colmaxs[HW];
  __shared__ float red[4];
  const int bid = blockIdx.x;
  const int g = bid >> 6, p = bid & 63;
  const int t = threadIdx.x, lane = t & 63, wid = t >> 6;
  const float* gp = gal + (size_t)g * ND * HW;
  const float* pp = prob + (size_t)p * ND * HW;
  float colmax = -3.4e38f;
  for (int y = 0; y < HW; ++y) {
    for (int k = t; k < ND; k += 256) prow[k] = pp[(size_t)k * HW + y];
    __syncthreads();
    float sv = -3.4e38f;
    if (t < HW) {
      sv = 0.f;
      for (int k = 0; k < ND; ++k) sv = fmaf(prow[k], gp[(size_t)k * HW + t], sv);
      colmax = fmaxf(colmax, sv);
    }
    float m = sv;
#pragma unroll
    for (int off = 1; off < 64; off <<= 1) m = fmaxf(m, __shfl_xor(m, off));
    if (lane == 0) red[wid] = m;
    __syncthreads();
    if (t == 0) rowmaxs[y] = fmaxf(fmaxf(red[0], red[1]), fmaxf(red[2], red[3]));
    __syncthreads();
  }
  if (t < HW) colmaxs[t] = colmax;
  __syncthreads();
  float partial = 0.f;
  for (int j = t; j < 2 * HW; j += 256) {
    const float v = (j < HW) ? colmaxs[j] : rowmaxs[j - HW];
    const float sc = (v - bn_m[0]) * (bn_w[0] / sqrtf(bn_v[0] + EPSV)) + bn_b[0];
    partial += sc * fc_w[j];
  }
#pragma unroll
  for (int off = 1; off < 64; off <<= 1) partial += __shfl_xor(partial, off);
  if (lane == 0) red[wid] = partial;
  __syncthreads();
  if (t == 0) {
    const float sum = fc_b[0] + red[0] + red[1] + red[2] + red[3];
    const float logit = (sum - lbn_m[0]) * (lbn_w[0] / sqrtf(lbn_v[0] + EPSV)) + lbn_b[0];
    out[bid] = 1.f / (1.f + expf(-logit * 0.1f));
  }
}

extern "C" void kernel_launch(void* const* d_in, const int* in_sizes, int n_in,
                              void* d_out, int out_size, void* d_ws, size_t ws_size,
                              hipStream_t stream) {
  const float* gal = (const float*)d_in[0];
  const float* prob = (const float*)d_in[1];
  const float* bn_w = (const float*)d_in[2];
  const float* bn_b = (const float*)d_in[3];
  const float* bn_m = (const float*)d_in[4];
  const float* bn_v = (const float*)d_in[5];
  const float* fc_w = (const float*)d_in[6];
  const float* fc_b = (const float*)d_in[7];
  const float* lbn_w = (const float*)d_in[8];
  const float* lbn_b = (const float*)d_in[9];
  const float* lbn_m = (const float*)d_in[10];
  const float* lbn_v = (const float*)d_in[11];
  float* out = (float*)d_out;

  const size_t ws_needed = (size_t)(NP + NG) * HW * ND * sizeof(_Float16);
  if (ws_size >= ws_needed) {
    _Float16* probT = (_Float16*)d_ws;
    _Float16* galT = probT + (size_t)NP * HW * ND;
    transpose_cvt_all<<<dim3(16, 6, NP + NG), dim3(256), 0, stream>>>(gal, prob, galT, probT);
    qaconv_main<<<dim3(NG * NP), dim3(512), 0, stream>>>(
        galT, probT, bn_w, bn_b, bn_m, bn_v, fc_w, fc_b, lbn_w, lbn_b, lbn_m, lbn_v, out);
  } else {
    qaconv_naive<<<dim3(NG * NP), dim3(256), 0, stream>>>(
        gal, prob, bn_w, bn_b, bn_m, bn_v, fc_w, fc_b, lbn_w, lbn_b, lbn_m, lbn_v, out);
  }
}

// Round 3
// 99.102 us; speedup vs baseline: 1.1910x; 1.1910x over previous
//
#include <hip/hip_runtime.h>
#include <hip/hip_bf16.h>
#include <cstdint>
#include <cstddef>

#define NG 32
#define NP 64
#define ND 512
#define HW 192
#define EPSV 1e-5f

typedef _Float16 half8 __attribute__((ext_vector_type(8)));
typedef float floatx4 __attribute__((ext_vector_type(4)));
typedef float floatx16 __attribute__((ext_vector_type(16)));

// ---------------- pre-pass: [B][ND][HW] f32 -> [B][HW][ND] fp16 (both tensors, one launch)
__global__ __launch_bounds__(256) void transpose_cvt_all(const float* __restrict__ gal,
                                                         const float* __restrict__ prob,
                                                         _Float16* __restrict__ galT,
                                                         _Float16* __restrict__ probT) {
  __shared__ float tile[32][33];
  const int z = blockIdx.z;
  const float* sp;
  _Float16* dp;
  if (z < NP) {
    sp = prob + (size_t)z * ND * HW;
    dp = probT + (size_t)z * HW * ND;
  } else {
    sp = gal + (size_t)(z - NP) * ND * HW;
    dp = galT + (size_t)(z - NP) * HW * ND;
  }
  const int k0 = blockIdx.x * 32;  // ND dim
  const int s0 = blockIdx.y * 32;  // HW dim
  const int tx = threadIdx.x & 31, ty = threadIdx.x >> 5;
#pragma unroll
  for (int i = ty; i < 32; i += 8)
    tile[i][tx] = sp[(size_t)(k0 + i) * HW + s0 + tx];
  __syncthreads();
#pragma unroll
  for (int i = ty; i < 32; i += 8)
    dp[(size_t)(s0 + i) * ND + k0 + tx] = (_Float16)tile[tx][i];
}

// ---------------- async 16B global -> LDS ----------------
__device__ __forceinline__ void g2l16(const void* g, void* l) {
  __builtin_amdgcn_global_load_lds(
      (const __attribute__((address_space(1))) void*)g,
      (__attribute__((address_space(3))) void*)l, 16, 0, 0);
}

// ---------------- main fused kernel: one WG (256 thr, 4 waves) per (g,p) ----------------
// A = probT[p] : [192][512] fp16 (rows = y), B = galT[g] : [192][512] (rows = x)
// S[y][x] = sum_k A[y][k] * B[x][k].  4 waves in 2(row) x 2(col) grid; each wave
// computes 96x96 via 3x3 fragment-pairs of mfma_f32_32x32x16_f16 (4 k-slices per
// K-tile of 64).  Single-buffered LDS (52 KB) -> 2 blocks/CU co-resident; the
// partner block hides this block's stage+barrier phase.
__global__ __launch_bounds__(256, 2) void qaconv_main(
    const _Float16* __restrict__ galT, const _Float16* __restrict__ probT,
    const float* __restrict__ bn_w, const float* __restrict__ bn_b,
    const float* __restrict__ bn_m, const float* __restrict__ bn_v,
    const float* __restrict__ fc_w, const float* __restrict__ fc_b,
    const float* __restrict__ lbn_w, const float* __restrict__ lbn_b,
    const float* __restrict__ lbn_m, const float* __restrict__ lbn_v,
    float* __restrict__ out) {
  // tiles: A [192 rows][64 halves = 8x16B slots], swizzled slot s^(row&7); B same.
  // After the K-loop the same storage is reused as rowbuf[192][66] f32.
  __shared__ __align__(16) char shraw[192 * 66 * 4];  // 50688 B >= 2*24576
  __shared__ float colpart[2][HW];
  __shared__ float wsum[4];
  char* tileA = shraw;
  char* tileB = shraw + 24576;
  float(*rowbuf)[66] = (float(*)[66])shraw;

  const int bid = blockIdx.x;
  const int g = bid >> 6, p = bid & 63;
  const int t = threadIdx.x;
  const int lane = t & 63, wid = t >> 6;
  const int wr = wid & 1;   // wave row: y-block of 96
  const int wc = wid >> 1;  // wave col: x-block of 96
  const int l31 = lane & 31, hi = lane >> 5;

  const _Float16* pA = probT + (size_t)p * HW * ND;
  const _Float16* pB = galT + (size_t)g * HW * ND;

  floatx16 acc[3][3];
#pragma unroll
  for (int i = 0; i < 3; ++i)
#pragma unroll
    for (int j = 0; j < 3; ++j) acc[i][j] = (floatx16)0.f;

  // staging geometry: 256 threads cover 32 rows x 8 slots per round; 6 rounds/op.
  const int srow = t >> 3;                  // 0..31
  const int s = (t & 7) ^ (srow & 7);       // pre-swizzled global source slot
  const _Float16* gA = pA + (size_t)srow * ND + s * 8;
  const _Float16* gB = pB + (size_t)srow * ND + s * 8;
  const int ldst = wid * 1024;  // wave-uniform LDS dest base (+ lane*16 by HW)

  for (int kt = 0; kt < 8; ++kt) {
    const int kb = kt * 64;
    __syncthreads();  // all waves finished reading previous tile
#pragma unroll
    for (int r = 0; r < 6; ++r) {
      g2l16(gA + (size_t)r * 32 * ND + kb, tileA + r * 4096 + ldst);
      g2l16(gB + (size_t)r * 32 * ND + kb, tileB + r * 4096 + ldst);
    }
    __syncthreads();  // vmcnt(0) drained: tile staged
#pragma unroll
    for (int kc = 0; kc < 4; ++kc) {
      half8 af[3], bf[3];
      const int sl = kc * 2 + hi;
#pragma unroll
      for (int f = 0; f < 3; ++f) {
        const int ra = wr * 96 + f * 32 + l31;
        af[f] = *(const half8*)(tileA + ra * 128 + ((sl ^ (ra & 7)) << 4));
        const int rb = wc * 96 + f * 32 + l31;
        bf[f] = *(const half8*)(tileB + rb * 128 + ((sl ^ (rb & 7)) << 4));
      }
      __builtin_amdgcn_s_setprio(1);
#pragma unroll
      for (int i = 0; i < 3; ++i)
#pragma unroll
        for (int j = 0; j < 3; ++j)
          acc[i][j] =
              __builtin_amdgcn_mfma_f32_32x32x16_f16(af[i], bf[j], acc[i][j], 0, 0, 0);
      __builtin_amdgcn_s_setprio(0);
    }
  }

  // ---- epilogue ----
  // C/D map (32x32): col X = wc*96 + fb*32 + (lane&31),
  //                  row Y = wr*96 + fa*32 + (e&3) + 8*(e>>2) + 4*hi,  e in [0,16)
  // colmax (max over Y, indexed by X):
  float cm[3];
#pragma unroll
  for (int fb = 0; fb < 3; ++fb) {
    float v = -3.4e38f;
#pragma unroll
    for (int fa = 0; fa < 3; ++fa)
#pragma unroll
      for (int e = 0; e < 16; ++e) v = fmaxf(v, acc[fa][fb][e]);
    v = fmaxf(v, __shfl_xor(v, 32));  // merge hi halves (rows +4)
    cm[fb] = v;
  }
  if (lane < 32) {
#pragma unroll
    for (int fb = 0; fb < 3; ++fb) colpart[wr][wc * 96 + fb * 32 + lane] = cm[fb];
  }

  // rowmax partials -> rowbuf (reuses tile LDS; must wait until all reads done)
  __syncthreads();
#pragma unroll
  for (int fa = 0; fa < 3; ++fa)
#pragma unroll
    for (int e = 0; e < 16; ++e) {
      const float rv =
          fmaxf(fmaxf(acc[fa][0][e], acc[fa][1][e]), acc[fa][2][e]);
      const int Y = wr * 96 + fa * 32 + (e & 3) + 8 * (e >> 2) + 4 * hi;
      rowbuf[Y][wc * 32 + l31] = rv;
    }
  __syncthreads();

  // ---- fixup + fused BN -> fc dot -> logit BN -> sigmoid ----
  float partial = 0.f;
  if (t < HW) {
    float rmax = -3.4e38f;
#pragma unroll
    for (int j = 0; j < 16; ++j) {
      const floatx4 v = *(const floatx4*)&rowbuf[t][j * 4];
      rmax = fmaxf(rmax, fmaxf(fmaxf(v[0], v[1]), fmaxf(v[2], v[3])));
    }
    const float cmax = fmaxf(colpart[0][t], colpart[1][t]);
    const float scale = bn_w[0] / sqrtf(bn_v[0] + EPSV);
    const float m = bn_m[0], b = bn_b[0];
    partial = ((cmax - m) * scale + b) * fc_w[t] +
              ((rmax - m) * scale + b) * fc_w[HW + t];
  }
#pragma unroll
  for (int off = 1; off < 64; off <<= 1) partial += __shfl_xor(partial, off);
  if (lane == 0) wsum[wid] = partial;
  __syncthreads();
  if (t == 0) {
    const float sum = fc_b[0] + wsum[0] + wsum[1] + wsum[2] + wsum[3];
    const float logit = (sum - lbn_m[0]) * (lbn_w[0] / sqrtf(lbn_v[0] + EPSV)) + lbn_b[0];
    out[bid] = 1.f / (1.f + expf(-logit * 0.1f));
  }
}

// ---------------- naive f32 fallback (only if ws too small) ----------------
__global__ __launch_bounds__(256) void qaconv_naive(
    const float* __restrict__ gal, const float* __restrict__ prob,
    const float* __restrict__ bn_w, const float* __restrict__ bn_b,
    const float* __restrict__ bn_m, const float* __restrict__ bn_v,
    const float* __restrict__ fc_w, const float* __restrict__ fc_b,
    const float* __restrict__ lbn_w, const float* __restrict__ lbn_b,
    const float* __restrict__ lbn_m, const float* __restrict__ lbn_v,
    float* __restrict__ out) {
  __shared__ float prow[ND];
  __shared__ float rowmaxs[HW];
  __shared__ float colmaxs[HW];
  __shared__ float red[4];
  const int bid = blockIdx.x;
  const int g = bid >> 6, p = bid & 63;
  const int t = threadIdx.x, lane = t & 63, wid = t >> 6;
  const float* gp = gal + (size_t)g * ND * HW;
  const float* pp = prob + (size_t)p * ND * HW;
  float colmax = -3.4e38f;
  for (int y = 0; y < HW; ++y) {
    for (int k = t; k < ND; k += 256) prow[k] = pp[(size_t)k * HW + y];
    __syncthreads();
    float sv = -3.4e38f;
    if (t < HW) {
      sv = 0.f;
      for (int k = 0; k < ND; ++k) sv = fmaf(prow[k], gp[(size_t)k * HW + t], sv);
      colmax = fmaxf(colmax, sv);
    }
    float m = sv;
#pragma unroll
    for (int off = 1; off < 64; off <<= 1) m = fmaxf(m, __shfl_xor(m, off));
    if (lane == 0) red[wid] = m;
    __syncthreads();
    if (t == 0) rowmaxs[y] = fmaxf(fmaxf(red[0], red[1]), fmaxf(red[2], red[3]));
    __syncthreads();
  }
  if (t < HW) colmaxs[t] = colmax;
  __syncthreads();
  float partial = 0.f;
  for (int j = t; j < 2 * HW; j += 256) {
    const float v = (j < HW) ? colmaxs[j] : rowmaxs[j - HW];
    const float sc = (v - bn_m[0]) * (bn_w[0] / sqrtf(bn_v[0] + EPSV)) + bn_b[0];
    partial += sc * fc_w[j];
  }
#pragma unroll
  for (int off = 1; off < 64; off <<= 1) partial += __shfl_xor(partial, off);
  if (lane == 0) red[wid] = partial;
  __syncthreads();
  if (t == 0) {
    const float sum = fc_b[0] + red[0] + red[1] + red[2] + red[3];
    const float logit = (sum - lbn_m[0]) * (lbn_w[0] / sqrtf(lbn_v[0] + EPSV)) + lbn_b[0];
    out[bid] = 1.f / (1.f + expf(-logit * 0.1f));
  }
}

extern "C" void kernel_launch(void* const* d_in, const int* in_sizes, int n_in,
                              void* d_out, int out_size, void* d_ws, size_t ws_size,
                              hipStream_t stream) {
  const float* gal = (const float*)d_in[0];
  const float* prob = (const float*)d_in[1];
  const float* bn_w = (const float*)d_in[2];
  const float* bn_b = (const float*)d_in[3];
  const float* bn_m = (const float*)d_in[4];
  const float* bn_v = (const float*)d_in[5];
  const float* fc_w = (const float*)d_in[6];
  const float* fc_b = (const float*)d_in[7];
  const float* lbn_w = (const float*)d_in[8];
  const float* lbn_b = (const float*)d_in[9];
  const float* lbn_m = (const float*)d_in[10];
  const float* lbn_v = (const float*)d_in[11];
  float* out = (float*)d_out;

  const size_t ws_needed = (size_t)(NP + NG) * HW * ND * sizeof(_Float16);
  if (ws_size >= ws_needed) {
    _Float16* probT = (_Float16*)d_ws;
    _Float16* galT = probT + (size_t)NP * HW * ND;
    transpose_cvt_all<<<dim3(16, 6, NP + NG), dim3(256), 0, stream>>>(gal, prob, galT, probT);
    qaconv_main<<<dim3(NG * NP), dim3(256), 0, stream>>>(
        galT, probT, bn_w, bn_b, bn_m, bn_v, fc_w, fc_b, lbn_w, lbn_b, lbn_m, lbn_v, out);
  } else {
    qaconv_naive<<<dim3(NG * NP), dim3(256), 0, stream>>>(
        gal, prob, bn_w, bn_b, bn_m, bn_v, fc_w, fc_b, lbn_w, lbn_b, lbn_m, lbn_v, out);
  }
}